// Round 1
// baseline (82.792 us; speedup 1.0000x reference)
//
#include <hip/hip_runtime.h>

// StateSpaceLayer: out[b,t,r,c] = sum_{j<=t} A[r]^(t-j) * x[b,j,r,c]
// == linear recurrence out[t] = A[r]*out[t-1] + x[t] along seq.
// Shapes: x (4,512,64,64) f32, A (64,) f32, out (4,512,64,64) f32.

#define B_   4
#define SEQ_ 512
#define D_   64
#define CHUNK_ 32
#define NWAVE_ (SEQ_ / CHUNK_)   // 16 waves -> 1024 threads/block

__global__ __launch_bounds__(NWAVE_ * 64) void ssm_scan_kernel(
    const float* __restrict__ x, const float* __restrict__ A,
    float* __restrict__ out)
{
    __shared__ float Elds[NWAVE_ * D_];   // chunk-end states, per wave per c

    const int blk = blockIdx.x;          // 0 .. B_*D_-1
    const int bi  = blk >> 6;            // batch index
    const int r   = blk & 63;            // row (decay) index
    const int tid = threadIdx.x;
    const int w   = tid >> 6;            // wave id = seq chunk id
    const int c   = tid & 63;            // lane = column (contiguous)

    const float a = fmaxf(A[r], 1e-6f);  // clip like reference (EPS=1e-6)

    const int j0 = w * CHUNK_;
    // flat index of x[bi, j, r, c] = ((bi*SEQ + j)*D + r)*D + c
    const size_t base = ((size_t)(bi * SEQ_ + j0) * D_ + r) * D_ + c;
    const float* xp = x + base;
    float*       op = out + base;
    const int jstride = D_ * D_;         // 4096 floats between timesteps

    // Phase 1: local scan of this chunk with zero initial state.
    float local[CHUNK_];
    float state = 0.0f;
    #pragma unroll
    for (int t = 0; t < CHUNK_; ++t) {
        float v = xp[(size_t)t * jstride];
        state = fmaf(state, a, v);       // state = a*state + v
        local[t] = state;
    }

    // Publish chunk-end state.
    Elds[w * D_ + c] = state;
    __syncthreads();

    // a^CHUNK_ (= a^32) via 5 squarings.
    float aL = a * a;   // a^2
    aL = aL * aL;       // a^4
    aL = aL * aL;       // a^8
    aL = aL * aL;       // a^16
    aL = aL * aL;       // a^32

    // Carry into this chunk = global state after chunk w-1:
    //   S_{w-1} = sum_{w'<w} aL^{(w-1-w')} * E_{w'}  (Horner, low->high)
    float carry = 0.0f;
    for (int wp = 0; wp < w; ++wp) {
        carry = fmaf(carry, aL, Elds[wp * D_ + c]);
    }

    // Phase 3: fix up with carry and store.  out[j0+t] = local[t] + carry*a^(t+1)
    float p = a;
    #pragma unroll
    for (int t = 0; t < CHUNK_; ++t) {
        op[(size_t)t * jstride] = fmaf(carry, p, local[t]);
        p *= a;
    }
}

extern "C" void kernel_launch(void* const* d_in, const int* in_sizes, int n_in,
                              void* d_out, int out_size, void* d_ws, size_t ws_size,
                              hipStream_t stream) {
    const float* x   = (const float*)d_in[0];
    const float* A   = (const float*)d_in[1];
    float*       out = (float*)d_out;

    dim3 grid(B_ * D_);            // 256 blocks, one per (batch, r)
    dim3 block(NWAVE_ * 64);       // 1024 threads = 16 waves
    hipLaunchKernelGGL(ssm_scan_kernel, grid, block, 0, stream, x, A, out);
}